// Round 1
// 694.851 us; speedup vs baseline: 1.1498x; 1.1498x over previous
//
#include <hip/hip_runtime.h>
#include <stdint.h>

// ---------------- problem constants ----------------
#define T_TOK 8192      // B*S
#define DIN   1024
#define DOUT  1024
#define HID   2048
#define NEXP  8
#define MAXN  8192      // worst-case tokens per expert

typedef __attribute__((ext_vector_type(8))) short short8;   // 8 bf16 (4 VGPRs)
typedef __attribute__((ext_vector_type(4))) float floatx4;  // MFMA accumulator

__device__ __forceinline__ ushort f2bf(float f) {
    uint32_t u = __float_as_uint(f);
    uint32_t r = (u + 0x7fffu + ((u >> 16) & 1u)) >> 16;   // RNE
    return (ushort)r;
}

// async global->LDS, 16B per lane; LDS dst is wave-uniform base + lane*16
__device__ __forceinline__ void load_lds_16(const ushort* g, ushort* l) {
    __builtin_amdgcn_global_load_lds(
        (const __attribute__((address_space(1))) void*)g,
        (__attribute__((address_space(3))) void*)l, 16, 0, 0);
}

// ---------------- fp32 -> bf16 plain convert (for x) ----------------
__global__ void convert_x_kernel(const float* __restrict__ in, ushort* __restrict__ out, int n4) {
    int i = blockIdx.x * blockDim.x + threadIdx.x;
    if (i >= n4) return;
    float4 v = ((const float4*)in)[i];
    ushort4 o;
    o.x = f2bf(v.x); o.y = f2bf(v.y); o.z = f2bf(v.z); o.w = f2bf(v.w);
    ((ushort4*)out)[i] = o;
}

// ---------------- fp32 [R,C] -> bf16 [C,R] tiled transpose ----------------
__global__ void transpose_bf16_kernel(const float* __restrict__ in, ushort* __restrict__ out,
                                      int R, int C) {
    __shared__ float tile[64][65];
    size_t base = (size_t)blockIdx.z * R * C;
    in  += base;
    out += base;
    int r0 = blockIdx.y * 64, c0 = blockIdx.x * 64;
    int t  = threadIdx.x;
    int rr = t >> 4;            // 0..15
    int cc = (t & 15) * 4;      // 0..60
    for (int p = 0; p < 4; p++) {
        int row = rr + p * 16;
        float4 v = *(const float4*)(in + (size_t)(r0 + row) * C + c0 + cc);
        tile[row][cc + 0] = v.x; tile[row][cc + 1] = v.y;
        tile[row][cc + 2] = v.z; tile[row][cc + 3] = v.w;
    }
    __syncthreads();
    for (int p = 0; p < 4; p++) {
        int orow = rr + p * 16;   // output row = original col index
        ushort4 o;
        o.x = f2bf(tile[cc + 0][orow]);
        o.y = f2bf(tile[cc + 1][orow]);
        o.z = f2bf(tile[cc + 2][orow]);
        o.w = f2bf(tile[cc + 3][orow]);
        *(ushort4*)(out + (size_t)(c0 + orow) * R + r0 + cc) = o;
    }
}

// ---------------- gate: logits -> softmax -> per-token top2 (NO atomics) ----------------
__global__ void gate_compute_kernel(const float* __restrict__ x, const float* __restrict__ gw,
                                    const float* __restrict__ gb, float* __restrict__ ew_out,
                                    int* __restrict__ te1, int* __restrict__ te2,
                                    float* __restrict__ tw1, float* __restrict__ tw2) {
    int gid  = blockIdx.x * blockDim.x + threadIdx.x;
    int t    = gid >> 6;
    int lane = threadIdx.x & 63;
    if (t >= T_TOK) return;
    float acc[8];
    #pragma unroll
    for (int e = 0; e < 8; e++) acc[e] = 0.f;
    const float* xrow = x + (size_t)t * DIN;
    #pragma unroll
    for (int i = 0; i < 16; i++) {
        int d = lane + i * 64;
        float xv = xrow[d];
        const float4* wr = (const float4*)(gw + (size_t)d * 8);
        float4 w0 = wr[0], w1 = wr[1];
        acc[0] += xv * w0.x; acc[1] += xv * w0.y; acc[2] += xv * w0.z; acc[3] += xv * w0.w;
        acc[4] += xv * w1.x; acc[5] += xv * w1.y; acc[6] += xv * w1.z; acc[7] += xv * w1.w;
    }
    #pragma unroll
    for (int e = 0; e < 8; e++)
        #pragma unroll
        for (int off = 32; off; off >>= 1) acc[e] += __shfl_xor(acc[e], off);
    if (lane == 0) {
        float l[8], mx = -1e30f;
        #pragma unroll
        for (int e = 0; e < 8; e++) { l[e] = acc[e] + gb[e]; mx = fmaxf(mx, l[e]); }
        float s = 0.f;
        #pragma unroll
        for (int e = 0; e < 8; e++) { l[e] = expf(l[e] - mx); s += l[e]; }
        float inv = 1.f / s;
        #pragma unroll
        for (int e = 0; e < 8; e++) { l[e] *= inv; ew_out[(size_t)t * 8 + e] = l[e]; }
        // top-2 (earliest index wins ties, matching lax.top_k)
        int i1 = 0;
        #pragma unroll
        for (int e = 1; e < 8; e++) if (l[e] > l[i1]) i1 = e;
        int i2 = (i1 == 0) ? 1 : 0;
        #pragma unroll
        for (int e = 0; e < 8; e++) if (e != i1 && l[e] > l[i2]) i2 = e;
        float s2 = l[i1] + l[i2];
        te1[t] = i1; tw1[t] = l[i1] / s2;
        te2[t] = i2; tw2[t] = l[i2] / s2;
    }
}

// ---------------- build expert lists: LDS histogram, 8 global atomics/block ----------------
__global__ void build_lists_kernel(const int* __restrict__ te1, const int* __restrict__ te2,
                                   const float* __restrict__ tw1, const float* __restrict__ tw2,
                                   int* __restrict__ counts, int* __restrict__ etok,
                                   float* __restrict__ ew) {
    __shared__ int lcnt[NEXP];
    __shared__ int gbase[NEXP];
    int tid = threadIdx.x;
    int t = blockIdx.x * 256 + tid;
    if (tid < NEXP) lcnt[tid] = 0;
    __syncthreads();
    int e1 = te1[t], e2 = te2[t];
    float w1 = tw1[t], w2 = tw2[t];
    int r1 = atomicAdd(&lcnt[e1], 1);   // LDS atomic
    int r2 = atomicAdd(&lcnt[e2], 1);
    __syncthreads();
    if (tid < NEXP) gbase[tid] = atomicAdd(&counts[tid], lcnt[tid]);  // 8 global atomics/block
    __syncthreads();
    int s1 = gbase[e1] + r1;
    etok[e1 * MAXN + s1] = t;
    ew  [e1 * MAXN + s1] = w1;
    int s2 = gbase[e2] + r2;
    etok[e2 * MAXN + s2] = t;
    ew  [e2 * MAXN + s2] = w2;
}

__global__ void prefix_kernel(const int* __restrict__ counts, int* __restrict__ offsets) {
    if (threadIdx.x == 0 && blockIdx.x == 0) {
        int o = 0;
        for (int e = 0; e < NEXP; e++) { offsets[e] = o; o += counts[e]; }
    }
}

// ================= 256x256 8-phase counted-vmcnt bf16 MFMA GEMM =================
// 512 threads = 8 waves (2M x 4N); per-wave C = 128x64 (acc[8][4] of 16x16 frags).
// LDS: ring of 4 half-K-tile slots, each slot = A[256][32] + B[256][32] bf16
//      (16 KB + 16 KB), total 128 KB. Slot layout = 16 blocks of 1 KB
//      (16 rows x 32 K); chunk c = lane holds M[blk*16 + (c&15)][(c>>4)*8 ..+7]
//      -> global_load_lds linear dst AND ds_read_b128 both lane-linear,
//      conflict-free (measured 0 conflicts in predecessor kernel).
// Schedule per iteration (K advance 128, 8 phases):
//   phases 2s,2s+1 consume slot s (mh=0/1); phases 2s+2,2s+3 (mod 8) stage
//   slot s's next content. Stage issue happens strictly AFTER the post-MFMA
//   barrier that follows slot s's lgkmcnt(0)-drained last reads (no overwrite
//   race). Consumption of slot s is gated by s_waitcnt vmcnt(8)+barrier at the
//   preceding odd-phase end: 12 outstanding loads -> retire slot s's 4, keep
//   8 in flight (never drains to 0 in the main loop: T3+T4). T5 setprio wraps
//   each 16-MFMA cluster.
// MODE 0: GEMM1 (z<8: gathered x rows -> relu -> h_buf; z==8: x -> sh_buf)
// MODE 1: GEMM2 (z<8: h_buf -> *w -> atomicAdd Out[token]; z==8: sh_buf -> atomicAdd Out[row])

#define STG(slot, j, kh) { \
    load_lds_16(srcA[j] + (size_t)(kh) * 32, dA[j] + (slot) * 8192); \
    load_lds_16(srcB[j] + (size_t)(kh) * 32, dB[j] + (slot) * 8192); }

#define LDA_FRAGS(slot, mh) { \
    const ushort* pa = &lA[(slot) * 8192 + (wave_m * 8 + (mh) * 4) * 512 + lane * 8]; \
    a[0] = *(const short8*)(pa +    0); a[1] = *(const short8*)(pa +  512); \
    a[2] = *(const short8*)(pa + 1024); a[3] = *(const short8*)(pa + 1536); }

#define LDB_FRAGS(slot) { \
    const ushort* pb = &lB[(slot) * 8192 + (wave_n * 4) * 512 + lane * 8]; \
    b[0] = *(const short8*)(pb +    0); b[1] = *(const short8*)(pb +  512); \
    b[2] = *(const short8*)(pb + 1024); b[3] = *(const short8*)(pb + 1536); }

#define MFMA16(mh) { \
    _Pragma("unroll") for (int mt = 0; mt < 4; ++mt) { \
      _Pragma("unroll") for (int nt = 0; nt < 4; ++nt) { \
        acc[(mh)*4+mt][nt] = __builtin_amdgcn_mfma_f32_16x16x32_bf16( \
            a[mt], b[nt], acc[(mh)*4+mt][nt], 0, 0, 0); } } }

#define PH_EVEN(slot, sslot, kh) { \
    LDA_FRAGS(slot, 0); LDB_FRAGS(slot); \
    STG(sslot, 0, kh); \
    __builtin_amdgcn_s_barrier(); \
    asm volatile("s_waitcnt lgkmcnt(0)" ::: "memory"); \
    __builtin_amdgcn_sched_barrier(0); \
    __builtin_amdgcn_s_setprio(1); \
    MFMA16(0); \
    __builtin_amdgcn_s_setprio(0); \
    __builtin_amdgcn_s_barrier(); \
    asm volatile("" ::: "memory"); }

#define PH_ODD(slot, sslot, kh) { \
    LDA_FRAGS(slot, 1); \
    STG(sslot, 1, kh); \
    __builtin_amdgcn_s_barrier(); \
    asm volatile("s_waitcnt lgkmcnt(0)" ::: "memory"); \
    __builtin_amdgcn_sched_barrier(0); \
    __builtin_amdgcn_s_setprio(1); \
    MFMA16(1); \
    __builtin_amdgcn_s_setprio(0); \
    asm volatile("s_waitcnt vmcnt(8)" ::: "memory"); \
    __builtin_amdgcn_s_barrier(); \
    asm volatile("" ::: "memory"); }

template <int MODE>
__global__ __launch_bounds__(512, 2)
void gemm8_kernel(const ushort* __restrict__ Ae, const ushort* __restrict__ Ash,
                  const ushort* __restrict__ Be, const ushort* __restrict__ Bsh,
                  const float* __restrict__ biase, const float* __restrict__ biass,
                  ushort* __restrict__ He, ushort* __restrict__ Hs,
                  float* __restrict__ Out,
                  const int* __restrict__ counts, const int* __restrict__ offsets,
                  const int* __restrict__ expert_tok, const float* __restrict__ expert_w) {
    constexpr int K  = (MODE == 0) ? DIN : HID;
    constexpr int NN = (MODE == 0) ? HID : DOUT;
    constexpr int NH = K / 32;     // # half-K slots of 32
    constexpr int J  = K / 128;    // 8-phase iterations

    const int z  = blockIdx.z;     // 0..7 routed expert, 8 = shared expert
    const int m0 = blockIdx.y * 256;
    const int n0 = blockIdx.x * 256;

    int cnt = T_TOK, rowbase = 0;
    const ushort* Aptr; const ushort* Bptr; const float* bptr;
    if (z < NEXP) {
        cnt = counts[z];
        if (m0 >= cnt) return;               // uniform early exit (before any barrier)
        rowbase = offsets[z];
        Aptr = Ae; Bptr = Be + (size_t)z * NN * K; bptr = biase + (size_t)z * NN;
    } else {
        Aptr = Ash; Bptr = Bsh; bptr = biass;
    }

    __shared__ ushort lA[4 * 8192];   // 64 KB: 4 slots x 16 KB
    __shared__ ushort lB[4 * 8192];   // 64 KB
    __shared__ int    rowA[256];
    __shared__ int    rowTok[256];
    __shared__ float  rowW[256];

    const int tid = threadIdx.x;
    if (tid < 256) {
        int g = m0 + tid;
        if (z < NEXP) {
            if constexpr (MODE == 0) {
                rowA[tid] = (g < cnt) ? expert_tok[z * MAXN + g] : 0;
            } else {
                rowA[tid]   = (g < cnt) ? (rowbase + g) : rowbase;
                rowTok[tid] = (g < cnt) ? expert_tok[z * MAXN + g] : 0;
                rowW[tid]   = (g < cnt) ? expert_w[z * MAXN + g] : 0.f;
            }
        } else {
            rowA[tid] = g;
        }
    }
    __syncthreads();

    const int w = tid >> 6, lane = tid & 63;
    const int lm = lane & 15, lq = lane >> 4;
    const int wave_m = w >> 2, wave_n = w & 3;   // 2 x 4 wave grid

    // producer: wave w, issue j stages 1 KB block (j*8 + w) of A and of B per slot
    const ushort* srcA[2]; const ushort* srcB[2];
    ushort* dA[2]; ushort* dB[2];
    #pragma unroll
    for (int j = 0; j < 2; ++j) {
        int blk = j * 8 + w;                    // 0..15
        srcA[j] = Aptr + (size_t)rowA[blk * 16 + lm] * K + lq * 8;
        srcB[j] = Bptr + (size_t)(n0 + blk * 16 + lm) * K + lq * 8;
        dA[j] = &lA[blk * 512];
        dB[j] = &lB[blk * 512];
    }

    floatx4 acc[8][4];
    #pragma unroll
    for (int i = 0; i < 8; ++i)
        #pragma unroll
        for (int jj = 0; jj < 4; ++jj) acc[i][jj] = (floatx4){0.f, 0.f, 0.f, 0.f};

    short8 a[4], b[4];

    // prologue: stage slots 0,1,2 (K-halves 0,1,2) = 12 loads/wave;
    // retire slot0's 4, keep 8 in flight (steady-state invariant)
    STG(0, 0, 0); STG(0, 1, 0);
    STG(1, 0, 1); STG(1, 1, 1);
    STG(2, 0, 2); STG(2, 1, 2);
    asm volatile("s_waitcnt vmcnt(8)" ::: "memory");
    __builtin_amdgcn_s_barrier();
    asm volatile("" ::: "memory");

    for (int j = 0; j < J; ++j) {
        int k4 = 4 * j;
        int kh3 = k4 + 3; if (kh3 > NH - 1) kh3 = NH - 1;   // clamp keeps vmcnt
        int kh4 = k4 + 4; if (kh4 > NH - 1) kh4 = NH - 1;   // bookkeeping exact at
        int kh5 = k4 + 5; if (kh5 > NH - 1) kh5 = NH - 1;   // the K-loop tail
        int kh6 = k4 + 6; if (kh6 > NH - 1) kh6 = NH - 1;
        PH_EVEN(0, 3, kh3);   // consume slot0, stage slot3 <- kh 4j+3
        PH_ODD (0, 3, kh3);   //   vmcnt(8): retires slot1 (needed next)
        PH_EVEN(1, 0, kh4);   // consume slot1, stage slot0 <- kh 4j+4
        PH_ODD (1, 0, kh4);   //   vmcnt(8): retires slot2
        PH_EVEN(2, 1, kh5);   // consume slot2, stage slot1 <- kh 4j+5
        PH_ODD (2, 1, kh5);   //   vmcnt(8): retires slot3
        PH_EVEN(3, 2, kh6);   // consume slot3, stage slot2 <- kh 4j+6
        PH_ODD (3, 2, kh6);   //   vmcnt(8): retires slot0 (for next iter)
    }

    asm volatile("s_waitcnt vmcnt(0)" ::: "memory");  // drain trailing (clamped) loads

    // epilogue: D[row = lq*4 + r][col = lane&15] per 16x16 fragment
    const int wn0 = wave_n * 64;
    #pragma unroll
    for (int mt8 = 0; mt8 < 8; ++mt8) {
        const int rl0 = wave_m * 128 + mt8 * 16 + lq * 4;
        #pragma unroll
        for (int nt = 0; nt < 4; ++nt) {
            const int col = n0 + wn0 + nt * 16 + lm;
            const float bv = bptr[col];
            #pragma unroll
            for (int r = 0; r < 4; ++r) {
                const int rl = rl0 + r;
                const int g  = m0 + rl;
                float v = acc[mt8][nt][r];
                if constexpr (MODE == 0) {
                    v = fmaxf(v + bv, 0.f);
                    if (z < NEXP) {
                        if (g < cnt) He[(size_t)(rowbase + g) * HID + col] = f2bf(v);
                    } else {
                        Hs[(size_t)g * HID + col] = f2bf(v);
                    }
                } else {
                    if (z < NEXP) {
                        if (g < cnt)
                            atomicAdd(&Out[(size_t)rowTok[rl] * DOUT + col], (v + bv) * rowW[rl]);
                    } else {
                        atomicAdd(&Out[(size_t)g * DOUT + col], v + bv);
                    }
                }
            }
        }
    }
}

// ---------------- launch ----------------
extern "C" void kernel_launch(void* const* d_in, const int* in_sizes, int n_in,
                              void* d_out, int out_size, void* d_ws, size_t ws_size,
                              hipStream_t stream) {
    const float* x   = (const float*)d_in[0];
    const float* gw  = (const float*)d_in[1];
    const float* gb  = (const float*)d_in[2];
    const float* ew1 = (const float*)d_in[3];
    const float* eb1 = (const float*)d_in[4];
    const float* ew2 = (const float*)d_in[5];
    const float* eb2 = (const float*)d_in[6];
    const float* sw1 = (const float*)d_in[7];
    const float* sb1 = (const float*)d_in[8];
    const float* sw2 = (const float*)d_in[9];
    const float* sb2 = (const float*)d_in[10];

    float* out_final = (float*)d_out;
    float* out_ew    = out_final + (size_t)T_TOK * DOUT;

    char* ws = (char*)d_ws;
    size_t off = 0;
    auto alloc = [&](size_t bytes) -> void* {
        void* p = ws + off;
        off += (bytes + 255) & ~(size_t)255;
        return p;
    };
    ushort* x_bf    = (ushort*)alloc((size_t)T_TOK * DIN * 2);
    ushort* ew1t    = (ushort*)alloc((size_t)NEXP * HID * DIN * 2);
    ushort* ew2t    = (ushort*)alloc((size_t)NEXP * DOUT * HID * 2);
    ushort* sw1t    = (ushort*)alloc((size_t)HID * DIN * 2);
    ushort* sw2t    = (ushort*)alloc((size_t)DOUT * HID * 2);
    ushort* h_buf   = (ushort*)alloc((size_t)T_TOK * 2 * HID * 2);   // 16384 rows
    ushort* sh_buf  = (ushort*)alloc((size_t)T_TOK * HID * 2);
    int*    counts  = (int*)alloc(NEXP * 4);
    int*    offsets = (int*)alloc(NEXP * 4);
    int*    etok    = (int*)alloc((size_t)NEXP * MAXN * 4);
    float*  ew      = (float*)alloc((size_t)NEXP * MAXN * 4);
    int*    te1     = (int*)alloc((size_t)T_TOK * 4);
    int*    te2     = (int*)alloc((size_t)T_TOK * 4);
    float*  tw1     = (float*)alloc((size_t)T_TOK * 4);
    float*  tw2     = (float*)alloc((size_t)T_TOK * 4);

    hipMemsetAsync(d_out, 0, (size_t)T_TOK * DOUT * 4, stream);   // final region only
    hipMemsetAsync(counts, 0, NEXP * 4, stream);

    convert_x_kernel<<<(T_TOK * DIN / 4) / 256, 256, 0, stream>>>(x, x_bf, T_TOK * DIN / 4);
    transpose_bf16_kernel<<<dim3(HID / 64, DIN / 64, NEXP), 256, 0, stream>>>(ew1, ew1t, DIN, HID);
    transpose_bf16_kernel<<<dim3(DOUT / 64, HID / 64, NEXP), 256, 0, stream>>>(ew2, ew2t, HID, DOUT);
    transpose_bf16_kernel<<<dim3(HID / 64, DIN / 64, 1), 256, 0, stream>>>(sw1, sw1t, DIN, HID);
    transpose_bf16_kernel<<<dim3(DOUT / 64, HID / 64, 1), 256, 0, stream>>>(sw2, sw2t, HID, DOUT);

    gate_compute_kernel<<<T_TOK / 4, 256, 0, stream>>>(x, gw, gb, out_ew, te1, te2, tw1, tw2);
    build_lists_kernel<<<T_TOK / 256, 256, 0, stream>>>(te1, te2, tw1, tw2, counts, etok, ew);
    prefix_kernel<<<1, 64, 0, stream>>>(counts, offsets);

    // fused GEMM1: z = 0..7 routed experts (gathered x), z = 8 shared expert
    gemm8_kernel<0><<<dim3(HID / 256, T_TOK / 256, NEXP + 1), 512, 0, stream>>>(
        x_bf, x_bf, ew1t, sw1t, eb1, sb1, h_buf, sh_buf, nullptr,
        counts, offsets, etok, ew);
    // fused GEMM2: z = 0..7 routed (h_buf, weighted atomic), z = 8 shared (sh_buf)
    gemm8_kernel<1><<<dim3(DOUT / 256, T_TOK / 256, NEXP + 1), 512, 0, stream>>>(
        h_buf, sh_buf, ew2t, sw2t, eb2, sb2, nullptr, nullptr, out_final,
        counts, offsets, etok, ew);
}